// Round 1
// baseline (786.857 us; speedup 1.0000x reference)
//
#include <hip/hip_runtime.h>
#include <hip/hip_bf16.h>

// Problem constants (fixed by reference)
#define B_  64
#define S_  1024
#define D_  1024   // ATT_DIM  (GEMM N)
#define K_  1024   // ATTEND_DIM / QUERY_DIM (GEMM K)

typedef unsigned short u16;
typedef short bf16x8 __attribute__((ext_vector_type(8)));
typedef float f32x4  __attribute__((ext_vector_type(4)));
typedef u16   u16x8  __attribute__((ext_vector_type(8)));
typedef u16   u16x4  __attribute__((ext_vector_type(4)));

// ---------------- workspace layout (byte offsets) ----------------
// target  : 65536 f32            [0,       262144)
// epart   : 65536*8 f32          [262144,  2359296)
// wcpart  : 64*8*1024 f32        [2359296, 4456448)
// wpre_bf : 1024*1024 u16        [4456448, 6553600)
// ctx_bf  : 64*1024*1024 u16     [6553600, 140771328)   (optional)
#define WS_TARGET 0
#define WS_EPART  262144
#define WS_WCPART 2359296
#define WS_WPRE   4456448
#define WS_CTXBF  6553600
#define WS_NEED_BF 140771328ull

__device__ __forceinline__ u16 f2bf(float f) {
    // round-to-nearest-even fp32 -> bf16 (no NaN handling needed: inputs finite)
    unsigned u = __float_as_uint(f);
    return (u16)((u + 0x7fffu + ((u >> 16) & 1u)) >> 16);
}

__device__ __forceinline__ float fast_tanh(float x) {
    // tanh(x) = 1 - 2/(e^{2x}+1); exact at +-inf, ~1e-7 abs err
    float t = __expf(2.0f * x);
    return 1.0f - 2.0f * __builtin_amdgcn_rcpf(t + 1.0f);
}

// ---------------- fp32 -> bf16 conversion (4 elems/thread) ----------------
__global__ void convert_bf16_kernel(const float* __restrict__ src, u16* __restrict__ dst) {
    size_t i = ((size_t)blockIdx.x * 256 + threadIdx.x) * 4;
    float4 v = *reinterpret_cast<const float4*>(src + i);
    u16x4 h = { f2bf(v.x), f2bf(v.y), f2bf(v.z), f2bf(v.w) };
    *reinterpret_cast<u16x4*>(dst + i) = h;
}

// ---------------- target = input @ W_q^T : one wave per (b,n) ----------------
__global__ void target_kernel(const float* __restrict__ inp, const float* __restrict__ wq,
                              float* __restrict__ target) {
    int tid  = threadIdx.x;
    int lane = tid & 63, wid = tid >> 6;
    int pair = blockIdx.x * 4 + wid;          // pair = b*1024 + n
    int b = pair >> 10, n = pair & 1023;
    const float* ir = inp + (size_t)b * K_;
    const float* wr = wq  + (size_t)n * K_;
    float acc = 0.f;
#pragma unroll
    for (int jj = 0; jj < 4; ++jj) {
        int off = jj * 256 + lane * 4;
        float4 a = *reinterpret_cast<const float4*>(ir + off);
        float4 w = *reinterpret_cast<const float4*>(wr + off);
        acc += a.x * w.x + a.y * w.y + a.z * w.z + a.w * w.w;
    }
#pragma unroll
    for (int off = 1; off < 64; off <<= 1) acc += __shfl_xor(acc, off);
    if (lane == 0) target[pair] = acc;
}

// ---------------- main GEMM + fused tanh/energy epilogue ----------------
// Block: 256 threads = 4 waves (2x2). Block tile 256(M) x 128(N), BK=32.
// Wave tile 128x64 = 8x4 grid of 16x16x32 MFMAs.
#define LDA 40   // padded LDS row stride in shorts (80 B, 16B aligned)

template<bool CTXBF>
__global__ __launch_bounds__(256, 2)
void gemm_ep_kernel(const float* __restrict__ ctxf, const u16* __restrict__ ctxb,
                    const u16* __restrict__ wpre, const float* __restrict__ bpre,
                    const float* __restrict__ wv,  const float* __restrict__ wcov,
                    const float* __restrict__ target, const float* __restrict__ cov,
                    float* __restrict__ pre_out, float* __restrict__ epart) {
    __shared__ __align__(16) u16 As[256 * LDA];
    __shared__ __align__(16) u16 Bs[128 * LDA];
    __shared__ float esm[256];

    const int tid  = threadIdx.x;
    const int lane = tid & 63;
    const int wid  = tid >> 6;
    const int wm = wid >> 1, wn = wid & 1;
    const int lr = lane & 15, quad = lane >> 4;
    const int m_base = blockIdx.y * 256;
    const int n_base = blockIdx.x * 128;
    const int b      = m_base >> 10;      // 256-row tile lies within one batch
    const int s_base = m_base & 1023;

    f32x4 acc[8][4];
#pragma unroll
    for (int i = 0; i < 8; ++i)
#pragma unroll
        for (int j = 0; j < 4; ++j) acc[i][j] = (f32x4){0.f, 0.f, 0.f, 0.f};

    esm[tid] = 0.0f;   // synced by first K-loop barrier

    for (int kt = 0; kt < 32; ++kt) {
        const int k0 = kt * 32;
        // ---- stage A (context rows m_base..m_base+255, k0..k0+31) ----
        if constexpr (CTXBF) {
            const int row0 = tid >> 2, kc = (tid & 3) * 8;
#pragma unroll
            for (int p = 0; p < 4; ++p) {
                int row = row0 + p * 64;
                u16x8 v = *reinterpret_cast<const u16x8*>(
                    ctxb + (size_t)(m_base + row) * K_ + k0 + kc);
                *reinterpret_cast<u16x8*>(&As[row * LDA + kc]) = v;
            }
        } else {
            const int row0 = tid >> 3, kc = (tid & 7) * 4;
#pragma unroll
            for (int p = 0; p < 8; ++p) {
                int row = row0 + p * 32;
                float4 v = *reinterpret_cast<const float4*>(
                    ctxf + (size_t)(m_base + row) * K_ + k0 + kc);
                u16x4 h = { f2bf(v.x), f2bf(v.y), f2bf(v.z), f2bf(v.w) };
                *reinterpret_cast<u16x4*>(&As[row * LDA + kc]) = h;
            }
        }
        // ---- stage B (W_pre rows n_base..n_base+127, bf16) ----
        {
            const int row0 = tid >> 2, kc = (tid & 3) * 8;
#pragma unroll
            for (int p = 0; p < 2; ++p) {
                int row = row0 + p * 64;
                u16x8 v = *reinterpret_cast<const u16x8*>(
                    wpre + (size_t)(n_base + row) * K_ + k0 + kc);
                *reinterpret_cast<u16x8*>(&Bs[row * LDA + kc]) = v;
            }
        }
        __syncthreads();
        // ---- fragments + MFMA ----
        bf16x8 af[8], bf[4];
#pragma unroll
        for (int i = 0; i < 8; ++i)
            af[i] = *reinterpret_cast<const bf16x8*>(&As[(wm * 128 + i * 16 + lr) * LDA + quad * 8]);
#pragma unroll
        for (int j = 0; j < 4; ++j)
            bf[j] = *reinterpret_cast<const bf16x8*>(&Bs[(wn * 64 + j * 16 + lr) * LDA + quad * 8]);
#pragma unroll
        for (int i = 0; i < 8; ++i)
#pragma unroll
            for (int j = 0; j < 4; ++j)
                acc[i][j] = __builtin_amdgcn_mfma_f32_16x16x32_bf16(af[i], bf[j], acc[i][j], 0, 0, 0);
        __syncthreads();
    }

    // ---- epilogue: +b_pre, store precompute, tanh, energy partial ----
    float bpre_j[4], wv_j[4], wcov_j[4], tgt_j[4];
    int n_j[4];
#pragma unroll
    for (int j = 0; j < 4; ++j) {
        n_j[j]    = n_base + wn * 64 + j * 16 + lr;
        bpre_j[j] = bpre[n_j[j]];
        wv_j[j]   = wv[n_j[j]];
        wcov_j[j] = wcov[n_j[j]];
        tgt_j[j]  = target[b * D_ + n_j[j]];
    }
#pragma unroll
    for (int i = 0; i < 8; ++i) {
#pragma unroll
        for (int r = 0; r < 4; ++r) {
            int row_local = wm * 128 + i * 16 + quad * 4 + r;
            int m = m_base + row_local;
            int s = s_base + row_local;
            float c = cov[b * S_ + s];
            float esum = 0.f;
#pragma unroll
            for (int j = 0; j < 4; ++j) {
                float pre = acc[i][j][r] + bpre_j[j];
                pre_out[(size_t)m * D_ + n_j[j]] = pre;
                float t = fast_tanh(pre + tgt_j[j] + c * wcov_j[j]);
                esum += t * wv_j[j];
            }
            // reduce over the 16 lanes sharing this row (lr dimension)
            esum += __shfl_xor(esum, 1);
            esum += __shfl_xor(esum, 2);
            esum += __shfl_xor(esum, 4);
            esum += __shfl_xor(esum, 8);
            if (lr == 0) atomicAdd(&esm[row_local], esum);
        }
    }
    __syncthreads();
    epart[(size_t)(m_base + tid) * 8 + blockIdx.x] = esm[tid];
}

// ---------------- softmax over S + coverage_new ----------------
__global__ void softmax_cov_kernel(const float* __restrict__ epart, const float* __restrict__ cov,
                                   float* __restrict__ score, float* __restrict__ covnew) {
    int b = blockIdx.x, t = threadIdx.x;
    int lane = t & 63, wid = t >> 6;
    __shared__ float red[4];
    float e[4];
    float lmax = -3.4e38f;
#pragma unroll
    for (int p = 0; p < 4; ++p) {
        int s = p * 256 + t;
        const float4* q = reinterpret_cast<const float4*>(epart + (size_t)(b * S_ + s) * 8);
        float4 a = q[0], c = q[1];
        e[p] = a.x + a.y + a.z + a.w + c.x + c.y + c.z + c.w;
        lmax = fmaxf(lmax, e[p]);
    }
#pragma unroll
    for (int off = 1; off < 64; off <<= 1) lmax = fmaxf(lmax, __shfl_xor(lmax, off));
    if (lane == 0) red[wid] = lmax;
    __syncthreads();
    float bm = fmaxf(fmaxf(red[0], red[1]), fmaxf(red[2], red[3]));
    __syncthreads();
    float ex[4];
    float lsum = 0.f;
#pragma unroll
    for (int p = 0; p < 4; ++p) { ex[p] = __expf(e[p] - bm); lsum += ex[p]; }
#pragma unroll
    for (int off = 1; off < 64; off <<= 1) lsum += __shfl_xor(lsum, off);
    if (lane == 0) red[wid] = lsum;
    __syncthreads();
    float total = red[0] + red[1] + red[2] + red[3];
    float inv = __builtin_amdgcn_rcpf(total);
#pragma unroll
    for (int p = 0; p < 4; ++p) {
        int s = p * 256 + t;
        float sc = ex[p] * inv;
        score[b * S_ + s]  = sc;
        covnew[b * S_ + s] = cov[b * S_ + s] + sc;
    }
}

// ---------------- weightedContext = score @ context ----------------
__global__ void wc_partial_kernel(const float* __restrict__ score, const float* __restrict__ ctx,
                                  float* __restrict__ part) {
    int sp = blockIdx.x, b = blockIdx.y, t = threadIdx.x;
    int col = t * 4;
    float ax = 0.f, ay = 0.f, az = 0.f, aw = 0.f;
    const float* base  = ctx + ((size_t)b * S_ + sp * 128) * K_ + col;
    const float* sbase = score + b * S_ + sp * 128;
    for (int ss = 0; ss < 128; ++ss) {
        float w = sbase[ss];
        float4 c = *reinterpret_cast<const float4*>(base + (size_t)ss * K_);
        ax += w * c.x; ay += w * c.y; az += w * c.z; aw += w * c.w;
    }
    float4 o = { ax, ay, az, aw };
    *reinterpret_cast<float4*>(part + (size_t)(b * 8 + sp) * 1024 + col) = o;
}

__global__ void wc_reduce_kernel(const float* __restrict__ part, float* __restrict__ wc) {
    int b = blockIdx.x, t = threadIdx.x;
    int col = t * 4;
    float ax = 0.f, ay = 0.f, az = 0.f, aw = 0.f;
#pragma unroll
    for (int p = 0; p < 8; ++p) {
        float4 v = *reinterpret_cast<const float4*>(part + (size_t)(b * 8 + p) * 1024 + col);
        ax += v.x; ay += v.y; az += v.z; aw += v.w;
    }
    float4 o = { ax, ay, az, aw };
    *reinterpret_cast<float4*>(wc + b * 1024 + col) = o;
}

// ---------------- host ----------------
extern "C" void kernel_launch(void* const* d_in, const int* in_sizes, int n_in,
                              void* d_out, int out_size, void* d_ws, size_t ws_size,
                              hipStream_t stream) {
    const float* input = (const float*)d_in[0];
    const float* ctx   = (const float*)d_in[1];
    const float* cov   = (const float*)d_in[2];
    const float* Wpre  = (const float*)d_in[3];
    const float* bpre  = (const float*)d_in[4];
    const float* Wq    = (const float*)d_in[5];
    const float* Wv    = (const float*)d_in[6];
    const float* Wcov  = (const float*)d_in[7];

    float* out        = (float*)d_out;
    float* out_wc     = out;                 // (B, 1024)
    float* out_score  = out + 65536;         // (B, S)
    float* out_covnew = out + 131072;        // (B, S)
    float* out_pre    = out + 196608;        // (B, S, D)

    char*  ws        = (char*)d_ws;
    float* ws_target = (float*)(ws + WS_TARGET);
    float* ws_epart  = (float*)(ws + WS_EPART);
    float* ws_wcpart = (float*)(ws + WS_WCPART);
    u16*   ws_wpre   = (u16*)(ws + WS_WPRE);
    u16*   ws_ctxbf  = (u16*)(ws + WS_CTXBF);

    const bool use_ctx_bf = (ws_size >= WS_NEED_BF);

    // 1. W_pre -> bf16 (1M elems)
    convert_bf16_kernel<<<1024, 256, 0, stream>>>(Wpre, ws_wpre);
    // 2. context -> bf16 (67.1M elems) if ws allows
    if (use_ctx_bf)
        convert_bf16_kernel<<<65536, 256, 0, stream>>>(ctx, ws_ctxbf);
    // 3. target = input @ W_q^T
    target_kernel<<<16384, 256, 0, stream>>>(input, Wq, ws_target);
    // 4. GEMM + fused tanh/energy epilogue
    dim3 ggrid(8, 256);   // x = n-tile (fast-varying for L2 locality), y = m-tile
    if (use_ctx_bf)
        gemm_ep_kernel<true><<<ggrid, 256, 0, stream>>>(ctx, ws_ctxbf, ws_wpre, bpre, Wv, Wcov,
                                                        ws_target, cov, out_pre, ws_epart);
    else
        gemm_ep_kernel<false><<<ggrid, 256, 0, stream>>>(ctx, ws_ctxbf, ws_wpre, bpre, Wv, Wcov,
                                                         ws_target, cov, out_pre, ws_epart);
    // 5. softmax + coverage_new
    softmax_cov_kernel<<<64, 256, 0, stream>>>(ws_epart, cov, out_score, out_covnew);
    // 6. weightedContext
    wc_partial_kernel<<<dim3(8, 64), 256, 0, stream>>>(out_score, ctx, ws_wcpart);
    wc_reduce_kernel<<<64, 256, 0, stream>>>(ws_wcpart, out_wc);
}

// Round 2
// 696.531 us; speedup vs baseline: 1.1297x; 1.1297x over previous
//
#include <hip/hip_runtime.h>
#include <hip/hip_bf16.h>

// Problem constants (fixed by reference)
#define B_  64
#define S_  1024
#define D_  1024   // ATT_DIM  (GEMM N)
#define K_  1024   // ATTEND_DIM / QUERY_DIM (GEMM K)

typedef unsigned short u16;
typedef short bf16x8 __attribute__((ext_vector_type(8)));
typedef float f32x4  __attribute__((ext_vector_type(4)));
typedef u16   u16x8  __attribute__((ext_vector_type(8)));
typedef u16   u16x4  __attribute__((ext_vector_type(4)));

// ---------------- workspace layout (byte offsets) ----------------
// target  : 65536 f32          [0,       262144)   target[n*64+b]
// epart   : 65536*8 f32        [262144,  2359296)
// wcpart  : 64*16*1024 f32     [2359296, 6553600)
// wpre_bf : 1024*1024 u16      [6553600, 8650752)
// ctx_bf  : 64*1024*1024 u16   [8650752, 142868480)  (optional)
#define WS_TARGET 0
#define WS_EPART  262144
#define WS_WCPART 2359296
#define WS_WPRE   6553600
#define WS_CTXBF  8650752
#define WS_NEED_BF 142868480ull

__device__ __forceinline__ u16 f2bf(float f) {
    unsigned u = __float_as_uint(f);
    return (u16)((u + 0x7fffu + ((u >> 16) & 1u)) >> 16);
}
__device__ __forceinline__ float bf2f(u16 h) {
    return __uint_as_float(((unsigned)h) << 16);
}
__device__ __forceinline__ float fast_tanh(float x) {
    float t = __expf(2.0f * x);
    return 1.0f - 2.0f * __builtin_amdgcn_rcpf(t + 1.0f);
}

// direct global->LDS DMA, 16 B per lane; LDS dest = wave-uniform base + lane*16
__device__ __forceinline__ void glds16(const void* g, void* l) {
    __builtin_amdgcn_global_load_lds(
        (__attribute__((address_space(1))) void*)(size_t)g,
        (__attribute__((address_space(3))) void*)(unsigned int)(size_t)l,
        16, 0, 0);
}

// ---------------- fp32 -> bf16 conversion (8 elems/thread, 16B stores) ----------------
__global__ void convert_bf16x8_kernel(const float* __restrict__ src, u16* __restrict__ dst) {
    size_t i = ((size_t)blockIdx.x * 256 + threadIdx.x) * 8;
    float4 a = *reinterpret_cast<const float4*>(src + i);
    float4 b = *reinterpret_cast<const float4*>(src + i + 4);
    u16x8 h = { f2bf(a.x), f2bf(a.y), f2bf(a.z), f2bf(a.w),
                f2bf(b.x), f2bf(b.y), f2bf(b.z), f2bf(b.w) };
    *reinterpret_cast<u16x8*>(dst + i) = h;
}

// ---------------- target[n*64+b] = dot(input[b], Wq[n]) ----------------
// pair = n*64+b so consecutive blocks share the same Wq row (L1/L2 hit).
__global__ void target_kernel(const float* __restrict__ inp, const float* __restrict__ wq,
                              float* __restrict__ target) {
    int tid  = threadIdx.x;
    int lane = tid & 63, wid = tid >> 6;
    int pair = blockIdx.x * 4 + wid;          // pair = n*64 + b
    int b = pair & 63, n = pair >> 6;
    const float* ir = inp + (size_t)b * K_;
    const float* wr = wq  + (size_t)n * K_;
    float acc = 0.f;
#pragma unroll
    for (int jj = 0; jj < 4; ++jj) {
        int off = jj * 256 + lane * 4;
        float4 a = *reinterpret_cast<const float4*>(ir + off);
        float4 w = *reinterpret_cast<const float4*>(wr + off);
        acc += a.x * w.x + a.y * w.y + a.z * w.z + a.w * w.w;
    }
#pragma unroll
    for (int off = 1; off < 64; off <<= 1) acc += __shfl_xor(acc, off);
    if (lane == 0) target[pair] = acc;
}

// ================= fast GEMM: global_load_lds staging, unpadded LDS =================
// Block: 256 threads = 4 waves (2x2). Block tile 256(M) x 128(N), BK=32.
// Wave tile 128x64 = 8x4 grid of 16x16x32 MFMAs.
__global__ __launch_bounds__(256, 2)
void gemm_ep_fast(const u16* __restrict__ ctxb, const u16* __restrict__ wpre,
                  const float* __restrict__ bpre, const float* __restrict__ wv,
                  const float* __restrict__ wcov, const float* __restrict__ target,
                  const float* __restrict__ cov, float* __restrict__ pre_out,
                  float* __restrict__ epart) {
    __shared__ __align__(16) u16 As[256 * 32];   // 16 KB, row stride 32 shorts (unpadded)
    __shared__ __align__(16) u16 Bs[128 * 32];   // 8 KB
    __shared__ float esm[256];

    const int tid  = threadIdx.x;
    const int lane = tid & 63;
    const int wid  = tid >> 6;
    const int wm = wid >> 1, wn = wid & 1;
    const int lr = lane & 15, quad = lane >> 4;
    const int m_base = blockIdx.y * 256;
    const int n_base = blockIdx.x * 128;
    const int b      = m_base >> 10;
    const int s_base = m_base & 1023;

    // staging source addresses: lane l -> row +l/4, col (l%4)*8 shorts (16 B)
    const int srow = lane >> 2;
    const int scol = (lane & 3) * 8;
    const u16* gA = ctxb + (size_t)(m_base + wid * 64 + srow) * K_ + scol;
    const u16* gB = wpre + (size_t)(n_base + wid * 32 + srow) * K_ + scol;
    u16* lA = &As[(wid * 64) * 32];
    u16* lB = &Bs[(wid * 32) * 32];

    f32x4 acc[8][4];
#pragma unroll
    for (int i = 0; i < 8; ++i)
#pragma unroll
        for (int j = 0; j < 4; ++j) acc[i][j] = (f32x4){0.f, 0.f, 0.f, 0.f};

    esm[tid] = 0.0f;   // made visible by first K-loop barrier

    for (int kt = 0; kt < 32; ++kt) {
        const int k0 = kt * 32;
        // A: 4 chunks of 16 rows (1 KB each) per wave -> 64 rows/wave
#pragma unroll
        for (int c = 0; c < 4; ++c)
            glds16(gA + (size_t)(c * 16) * K_ + k0, lA + c * 16 * 32);
        // B: 2 chunks of 16 rows per wave -> 32 rows/wave
#pragma unroll
        for (int c = 0; c < 2; ++c)
            glds16(gB + (size_t)(c * 16) * K_ + k0, lB + c * 16 * 32);
        __syncthreads();   // drains vmcnt (global_load_lds) + lgkm

        bf16x8 af[8], bfr[4];
#pragma unroll
        for (int i = 0; i < 8; ++i)
            af[i] = *reinterpret_cast<const bf16x8*>(&As[(wm * 128 + i * 16 + lr) * 32 + quad * 8]);
#pragma unroll
        for (int j = 0; j < 4; ++j)
            bfr[j] = *reinterpret_cast<const bf16x8*>(&Bs[(wn * 64 + j * 16 + lr) * 32 + quad * 8]);
#pragma unroll
        for (int i = 0; i < 8; ++i)
#pragma unroll
            for (int j = 0; j < 4; ++j)
                acc[i][j] = __builtin_amdgcn_mfma_f32_16x16x32_bf16(af[i], bfr[j], acc[i][j], 0, 0, 0);
        __syncthreads();
    }

    // ---- epilogue: +b_pre, store precompute (non-temporal), tanh, energy partial ----
    float bpre_j[4], wv_j[4], wcov_j[4], tgt_j[4];
    int n_j[4];
#pragma unroll
    for (int j = 0; j < 4; ++j) {
        n_j[j]    = n_base + wn * 64 + j * 16 + lr;
        bpre_j[j] = bpre[n_j[j]];
        wv_j[j]   = wv[n_j[j]];
        wcov_j[j] = wcov[n_j[j]];
        tgt_j[j]  = target[n_j[j] * 64 + b];
    }
#pragma unroll
    for (int i = 0; i < 8; ++i) {
#pragma unroll
        for (int r = 0; r < 4; ++r) {
            int row_local = wm * 128 + i * 16 + quad * 4 + r;
            int m = m_base + row_local;
            int s = s_base + row_local;
            float c = cov[b * S_ + s];
            float esum = 0.f;
#pragma unroll
            for (int j = 0; j < 4; ++j) {
                float pre = acc[i][j][r] + bpre_j[j];
                __builtin_nontemporal_store(pre, &pre_out[(size_t)m * D_ + n_j[j]]);
                float t = fast_tanh(pre + tgt_j[j] + c * wcov_j[j]);
                esum += t * wv_j[j];
            }
            esum += __shfl_xor(esum, 1);
            esum += __shfl_xor(esum, 2);
            esum += __shfl_xor(esum, 4);
            esum += __shfl_xor(esum, 8);
            if (lr == 0) atomicAdd(&esm[row_local], esum);
        }
    }
    __syncthreads();
    epart[(size_t)(m_base + tid) * 8 + blockIdx.x] = esm[tid];
}

// ================= fallback GEMM (fp32 inputs, manual staging) =================
#define LDA 40
__global__ __launch_bounds__(256, 2)
void gemm_ep_fallback(const float* __restrict__ ctxf, const u16* __restrict__ wpre,
                      const float* __restrict__ bpre, const float* __restrict__ wv,
                      const float* __restrict__ wcov, const float* __restrict__ target,
                      const float* __restrict__ cov, float* __restrict__ pre_out,
                      float* __restrict__ epart) {
    __shared__ __align__(16) u16 As[256 * LDA];
    __shared__ __align__(16) u16 Bs[128 * LDA];
    __shared__ float esm[256];
    const int tid  = threadIdx.x;
    const int lane = tid & 63;
    const int wid  = tid >> 6;
    const int wm = wid >> 1, wn = wid & 1;
    const int lr = lane & 15, quad = lane >> 4;
    const int m_base = blockIdx.y * 256;
    const int n_base = blockIdx.x * 128;
    const int b      = m_base >> 10;
    const int s_base = m_base & 1023;

    f32x4 acc[8][4];
#pragma unroll
    for (int i = 0; i < 8; ++i)
#pragma unroll
        for (int j = 0; j < 4; ++j) acc[i][j] = (f32x4){0.f, 0.f, 0.f, 0.f};
    esm[tid] = 0.0f;

    for (int kt = 0; kt < 32; ++kt) {
        const int k0 = kt * 32;
        {
            const int row0 = tid >> 3, kc = (tid & 7) * 4;
#pragma unroll
            for (int p = 0; p < 8; ++p) {
                int row = row0 + p * 32;
                float4 v = *reinterpret_cast<const float4*>(
                    ctxf + (size_t)(m_base + row) * K_ + k0 + kc);
                u16x4 h = { f2bf(v.x), f2bf(v.y), f2bf(v.z), f2bf(v.w) };
                *reinterpret_cast<u16x4*>(&As[row * LDA + kc]) = h;
            }
        }
        {
            const int row0 = tid >> 2, kc = (tid & 3) * 8;
#pragma unroll
            for (int p = 0; p < 2; ++p) {
                int row = row0 + p * 64;
                u16x8 v = *reinterpret_cast<const u16x8*>(
                    wpre + (size_t)(n_base + row) * K_ + k0 + kc);
                *reinterpret_cast<u16x8*>(&Bs[row * LDA + kc]) = v;
            }
        }
        __syncthreads();
        bf16x8 af[8], bfr[4];
#pragma unroll
        for (int i = 0; i < 8; ++i)
            af[i] = *reinterpret_cast<const bf16x8*>(&As[(wm * 128 + i * 16 + lr) * LDA + quad * 8]);
#pragma unroll
        for (int j = 0; j < 4; ++j)
            bfr[j] = *reinterpret_cast<const bf16x8*>(&Bs[(wn * 64 + j * 16 + lr) * LDA + quad * 8]);
#pragma unroll
        for (int i = 0; i < 8; ++i)
#pragma unroll
            for (int j = 0; j < 4; ++j)
                acc[i][j] = __builtin_amdgcn_mfma_f32_16x16x32_bf16(af[i], bfr[j], acc[i][j], 0, 0, 0);
        __syncthreads();
    }
    float bpre_j[4], wv_j[4], wcov_j[4], tgt_j[4];
    int n_j[4];
#pragma unroll
    for (int j = 0; j < 4; ++j) {
        n_j[j]    = n_base + wn * 64 + j * 16 + lr;
        bpre_j[j] = bpre[n_j[j]];
        wv_j[j]   = wv[n_j[j]];
        wcov_j[j] = wcov[n_j[j]];
        tgt_j[j]  = target[n_j[j] * 64 + b];
    }
#pragma unroll
    for (int i = 0; i < 8; ++i) {
#pragma unroll
        for (int r = 0; r < 4; ++r) {
            int row_local = wm * 128 + i * 16 + quad * 4 + r;
            int m = m_base + row_local;
            int s = s_base + row_local;
            float c = cov[b * S_ + s];
            float esum = 0.f;
#pragma unroll
            for (int j = 0; j < 4; ++j) {
                float pre = acc[i][j][r] + bpre_j[j];
                __builtin_nontemporal_store(pre, &pre_out[(size_t)m * D_ + n_j[j]]);
                float t = fast_tanh(pre + tgt_j[j] + c * wcov_j[j]);
                esum += t * wv_j[j];
            }
            esum += __shfl_xor(esum, 1);
            esum += __shfl_xor(esum, 2);
            esum += __shfl_xor(esum, 4);
            esum += __shfl_xor(esum, 8);
            if (lr == 0) atomicAdd(&esm[row_local], esum);
        }
    }
    __syncthreads();
    epart[(size_t)(m_base + tid) * 8 + blockIdx.x] = esm[tid];
}

// ---------------- softmax over S + coverage_new ----------------
__global__ void softmax_cov_kernel(const float* __restrict__ epart, const float* __restrict__ cov,
                                   float* __restrict__ score, float* __restrict__ covnew) {
    int b = blockIdx.x, t = threadIdx.x;
    int lane = t & 63, wid = t >> 6;
    __shared__ float red[4];
    float e[4];
    float lmax = -3.4e38f;
#pragma unroll
    for (int p = 0; p < 4; ++p) {
        int s = p * 256 + t;
        const float4* q = reinterpret_cast<const float4*>(epart + (size_t)(b * S_ + s) * 8);
        float4 a = q[0], c = q[1];
        e[p] = a.x + a.y + a.z + a.w + c.x + c.y + c.z + c.w;
        lmax = fmaxf(lmax, e[p]);
    }
#pragma unroll
    for (int off = 1; off < 64; off <<= 1) lmax = fmaxf(lmax, __shfl_xor(lmax, off));
    if (lane == 0) red[wid] = lmax;
    __syncthreads();
    float bm = fmaxf(fmaxf(red[0], red[1]), fmaxf(red[2], red[3]));
    __syncthreads();
    float ex[4];
    float lsum = 0.f;
#pragma unroll
    for (int p = 0; p < 4; ++p) { ex[p] = __expf(e[p] - bm); lsum += ex[p]; }
#pragma unroll
    for (int off = 1; off < 64; off <<= 1) lsum += __shfl_xor(lsum, off);
    if (lane == 0) red[wid] = lsum;
    __syncthreads();
    float total = red[0] + red[1] + red[2] + red[3];
    float inv = __builtin_amdgcn_rcpf(total);
#pragma unroll
    for (int p = 0; p < 4; ++p) {
        int s = p * 256 + t;
        float sc = ex[p] * inv;
        score[b * S_ + s]  = sc;
        covnew[b * S_ + s] = cov[b * S_ + s] + sc;
    }
}

// ---------------- weightedContext = score @ context ----------------
__global__ void wc_partial_bf(const float* __restrict__ score, const u16* __restrict__ ctxb,
                              float* __restrict__ part) {
    int sp = blockIdx.x, b = blockIdx.y, t = threadIdx.x;   // sp in [0,16)
    int col = t * 4;
    float ax = 0.f, ay = 0.f, az = 0.f, aw = 0.f;
    const u16*   base  = ctxb + ((size_t)b * S_ + sp * 64) * K_ + col;
    const float* sbase = score + b * S_ + sp * 64;
    for (int ss = 0; ss < 64; ++ss) {
        float w = sbase[ss];
        u16x4 c = *reinterpret_cast<const u16x4*>(base + (size_t)ss * K_);
        ax += w * bf2f(c[0]); ay += w * bf2f(c[1]);
        az += w * bf2f(c[2]); aw += w * bf2f(c[3]);
    }
    float4 o = { ax, ay, az, aw };
    *reinterpret_cast<float4*>(part + (size_t)(b * 16 + sp) * 1024 + col) = o;
}

__global__ void wc_partial_f32(const float* __restrict__ score, const float* __restrict__ ctx,
                               float* __restrict__ part) {
    int sp = blockIdx.x, b = blockIdx.y, t = threadIdx.x;
    int col = t * 4;
    float ax = 0.f, ay = 0.f, az = 0.f, aw = 0.f;
    const float* base  = ctx + ((size_t)b * S_ + sp * 64) * K_ + col;
    const float* sbase = score + b * S_ + sp * 64;
    for (int ss = 0; ss < 64; ++ss) {
        float w = sbase[ss];
        float4 c = *reinterpret_cast<const float4*>(base + (size_t)ss * K_);
        ax += w * c.x; ay += w * c.y; az += w * c.z; aw += w * c.w;
    }
    float4 o = { ax, ay, az, aw };
    *reinterpret_cast<float4*>(part + (size_t)(b * 16 + sp) * 1024 + col) = o;
}

__global__ void wc_reduce_kernel(const float* __restrict__ part, float* __restrict__ wc) {
    int b = blockIdx.x, t = threadIdx.x;
    int col = t * 4;
    float ax = 0.f, ay = 0.f, az = 0.f, aw = 0.f;
#pragma unroll
    for (int p = 0; p < 16; ++p) {
        float4 v = *reinterpret_cast<const float4*>(part + (size_t)(b * 16 + p) * 1024 + col);
        ax += v.x; ay += v.y; az += v.z; aw += v.w;
    }
    float4 o = { ax, ay, az, aw };
    *reinterpret_cast<float4*>(wc + b * 1024 + col) = o;
}

// ---------------- host ----------------
extern "C" void kernel_launch(void* const* d_in, const int* in_sizes, int n_in,
                              void* d_out, int out_size, void* d_ws, size_t ws_size,
                              hipStream_t stream) {
    const float* input = (const float*)d_in[0];
    const float* ctx   = (const float*)d_in[1];
    const float* cov   = (const float*)d_in[2];
    const float* Wpre  = (const float*)d_in[3];
    const float* bpre  = (const float*)d_in[4];
    const float* Wq    = (const float*)d_in[5];
    const float* Wv    = (const float*)d_in[6];
    const float* Wcov  = (const float*)d_in[7];

    float* out        = (float*)d_out;
    float* out_wc     = out;                 // (B, 1024)
    float* out_score  = out + 65536;         // (B, S)
    float* out_covnew = out + 131072;        // (B, S)
    float* out_pre    = out + 196608;        // (B, S, D)

    char*  ws        = (char*)d_ws;
    float* ws_target = (float*)(ws + WS_TARGET);
    float* ws_epart  = (float*)(ws + WS_EPART);
    float* ws_wcpart = (float*)(ws + WS_WCPART);
    u16*   ws_wpre   = (u16*)(ws + WS_WPRE);
    u16*   ws_ctxbf  = (u16*)(ws + WS_CTXBF);

    const bool use_bf = (ws_size >= WS_NEED_BF);

    // 1. W_pre -> bf16 (1M elems, 8/thread)
    convert_bf16x8_kernel<<<512, 256, 0, stream>>>(Wpre, ws_wpre);
    // 2. context -> bf16 (67.1M elems)
    if (use_bf)
        convert_bf16x8_kernel<<<32768, 256, 0, stream>>>(ctx, ws_ctxbf);
    // 3. target = input @ W_q^T  (stored target[n*64+b])
    target_kernel<<<16384, 256, 0, stream>>>(input, Wq, ws_target);
    // 4. GEMM + fused tanh/energy epilogue
    dim3 ggrid(8, 256);
    if (use_bf)
        gemm_ep_fast<<<ggrid, 256, 0, stream>>>(ws_ctxbf, ws_wpre, bpre, Wv, Wcov,
                                                ws_target, cov, out_pre, ws_epart);
    else
        gemm_ep_fallback<<<ggrid, 256, 0, stream>>>(ctx, ws_wpre, bpre, Wv, Wcov,
                                                    ws_target, cov, out_pre, ws_epart);
    // 5. softmax + coverage_new
    softmax_cov_kernel<<<64, 256, 0, stream>>>(ws_epart, cov, out_score, out_covnew);
    // 6. weightedContext
    if (use_bf)
        wc_partial_bf<<<dim3(16, 64), 256, 0, stream>>>(out_score, ws_ctxbf, ws_wcpart);
    else
        wc_partial_f32<<<dim3(16, 64), 256, 0, stream>>>(out_score, ctx, ws_wcpart);
    wc_reduce_kernel<<<64, 256, 0, stream>>>(ws_wcpart, out_wc);
}